// Round 16
// baseline (383.502 us; speedup 1.0000x reference)
//
#include <hip/hip_runtime.h>
#include <hip/hip_bf16.h>

// ---------------------------------------------------------------------------
// EncoderLayer on MI355X (gfx950), bf16 MFMA pipeline.
//   x[4,2048,1024] -> QKV proj -> MHA (flash, fixed-max softmax) -> Wc+bias+res
//   -> RMSNorm -> gated MLP (silu(h@L1.T)*(h@L2.T))@L3.T + res -> RMSNorm
// ---------------------------------------------------------------------------

#define EMB   1024
#define HEADS 16
#define DK    64
#define INNER 2816
#define BATCH 4
#define NTOK  2048
#define MROWS (BATCH * NTOK)   // 8192

// q pre-scale: 1/sqrt(64) * log2(e)  (softmax done in exp2 domain)
#define QSCALE 0.18033688011112042f

typedef short bf16x8 __attribute__((ext_vector_type(8)));
typedef short s16x4  __attribute__((ext_vector_type(4)));
typedef float f32x4  __attribute__((ext_vector_type(4)));

typedef const void __attribute__((address_space(1)))* gas_cvp;
typedef void       __attribute__((address_space(3)))* las_vp;

__device__ __forceinline__ short to_bf16(float f) {
  union { float f; unsigned u; } x; x.f = f;
  unsigned r = x.u + 0x7FFFu + ((x.u >> 16) & 1u);   // RNE
  return (short)(r >> 16);
}

__device__ __forceinline__ float from_bf16(short s) {
  union { unsigned u; float f; } x;
  x.u = ((unsigned)(unsigned short)s) << 16;
  return x.f;
}

// packed f32x2 -> bf16x2 (low = a, high = b)
__device__ __forceinline__ unsigned cvt_pk_bf16(float a, float b) {
  unsigned r;
  asm("v_cvt_pk_bf16_f32 %0, %1, %2" : "=v"(r) : "v"(a), "v"(b));
  return r;
}

// raw v_exp_f32 (2^x): 1 instruction, flush-to-zero below 2^-126 (fine here;
// libm exp2f expands to a denormal-safe multi-inst sequence we don't need)
__device__ __forceinline__ float exp2_raw(float x) {
#if __has_builtin(__builtin_amdgcn_exp2f)
  return __builtin_amdgcn_exp2f(x);
#else
  float r;
  asm("v_exp_f32 %0, %1" : "=v"(r) : "v"(x));
  return r;
#endif
}

// async global->LDS, 16B per lane; LDS dest must be linear (base + lane*16)
__device__ __forceinline__ void gld16(void* lds, const void* g) {
  __builtin_amdgcn_global_load_lds((gas_cvp)g, (las_vp)lds, 16, 0, 0);
}

// ---------------------------------------------------------------------------
// Merged f32 -> bf16 conversions (one launch).
// ---------------------------------------------------------------------------
__global__ __launch_bounds__(256, 4)
void cvt_all(const float* __restrict__ x,  const float* __restrict__ Wq,
             const float* __restrict__ Wk, const float* __restrict__ Wv,
             const float* __restrict__ Wc, const float* __restrict__ L1,
             const float* __restrict__ L2, const float* __restrict__ L3,
             short* __restrict__ xb, short* __restrict__ wqkv,
             short* __restrict__ wcb, short* __restrict__ l12,
             short* __restrict__ l3b)
{
  const int blk = blockIdx.x, tt = threadIdx.x;
  auto conv4 = [&](const float* s, short* d, int i) {
    float4 v = ((const float4*)s)[i];
    s16x4 o;
    o[0] = to_bf16(v.x); o[1] = to_bf16(v.y);
    o[2] = to_bf16(v.z); o[3] = to_bf16(v.w);
    ((s16x4*)d)[i] = o;
  };
  if (blk < 8192)       conv4(x,  xb,                 blk * 256 + tt);
  else if (blk < 9216)  conv4(Wq, wqkv,               (blk - 8192) * 256 + tt);
  else if (blk < 10240) conv4(Wk, wqkv + 1024 * 1024, (blk - 9216) * 256 + tt);
  else if (blk < 11264) conv4(Wv, wqkv + 2 * 1024 * 1024, (blk - 10240) * 256 + tt);
  else if (blk < 12288) conv4(Wc, wcb,                (blk - 11264) * 256 + tt);
  else if (blk < 15104) conv4(L3, l3b,                (blk - 12288) * 256 + tt);
  else {
    int i = (blk - 15104) * 256 + tt;      // over INNER*256 float4 slots
    int row = i >> 8, c4 = i & 255;
    float4 v1 = ((const float4*)L1)[i];
    float4 v2 = ((const float4*)L2)[i];
    s16x4 o1, o2;
    o1[0]=to_bf16(v1.x); o1[1]=to_bf16(v1.y); o1[2]=to_bf16(v1.z); o1[3]=to_bf16(v1.w);
    o2[0]=to_bf16(v2.x); o2[1]=to_bf16(v2.y); o2[2]=to_bf16(v2.z); o2[3]=to_bf16(v2.w);
    ((s16x4*)l12)[(size_t)(2 * row) * 256 + c4]     = o1;
    ((s16x4*)l12)[(size_t)(2 * row + 1) * 256 + c4] = o2;
  }
}

// ---------------------------------------------------------------------------
// 128x128 GEMM (m97 structure), C[M,N] = A[M,K] @ B[N,K]^T, BK=64.
// XCD-swizzled block mapping (grid % 8 == 0).
// Epilogues stage the wave's output sub-tile through the dead LDS tile and
// flush with bf16x8 stores (16B/lane, 128B contiguous per 8 lanes) -- the
// old scalar b16 scatters were ~25% store efficiency.
// MODE 0: QKV  -> out0=q(pre-scaled), out1=k std, out2=v transposed [b,h,d,tok]
// MODE 1: Wc   -> out0 = bf16(acc + bc[n](aux1) + x[m,n](aux0))
// MODE 2: MLP12 interleaved u,g -> out0 = bf16(silu(u)*g), N/2 cols
// MODE 3: L3   -> out0 = bf16(acc + bf16(hb[m,n])(auxb))
// ---------------------------------------------------------------------------
template<int MODE>
__global__ __launch_bounds__(256, 3)
void gemm_bt(const short* __restrict__ A, const short* __restrict__ Bw,
             int M, int N, int K,
             void* __restrict__ out0, void* __restrict__ out1,
             void* __restrict__ out2,
             const float* __restrict__ aux0, const float* __restrict__ aux1,
             const short* __restrict__ auxb)
{
  __shared__ short smem[2 * 128 * 64];     // At | Bt (contiguous for strips)
  short* At = smem;
  short* Bt = smem + 128 * 64;
  const int t = threadIdx.x;
  const int lane = t & 63;
  const int l15 = lane & 15, lhi = lane >> 4;
  const int w  = t >> 6;
  const int wm = (w >> 1) << 6;
  const int wn = (w & 1) << 6;
  // bijective XCD swizzle: consecutive wg on one XCD share A panels
  const int chunk = gridDim.x >> 3;
  const int wg = (blockIdx.x & 7) * chunk + (blockIdx.x >> 3);
  const int tilesN = N >> 7;
  const int m0 = (wg / tilesN) << 7;
  const int n0 = (wg % tilesN) << 7;

  const int r = t >> 3;
  const int p = t & 7;
  const int psrc = p ^ (r & 7);
  const short* Ag = A  + (size_t)(m0 + r) * K + psrc * 8;
  const short* Bg = Bw + (size_t)(n0 + r) * K + psrc * 8;

  f32x4 acc[4][4];
  const f32x4 fz = {0.f, 0.f, 0.f, 0.f};
#pragma unroll
  for (int i = 0; i < 4; i++)
#pragma unroll
    for (int j = 0; j < 4; j++) acc[i][j] = fz;

  int aoff[2][4], boff[2][4];
#pragma unroll
  for (int kk = 0; kk < 2; kk++)
#pragma unroll
    for (int mt = 0; mt < 4; mt++) {
      int ra = wm + mt * 16 + l15;
      aoff[kk][mt] = ra * 128 + ((kk * 64 + lhi * 16) ^ ((ra & 7) << 4));
      int rb = wn + mt * 16 + l15;
      boff[kk][mt] = rb * 128 + ((kk * 64 + lhi * 16) ^ ((rb & 7) << 4));
    }

  for (int k0 = 0; k0 < K; k0 += 64) {
#pragma unroll
    for (int i = 0; i < 4; i++) {
      gld16((char*)At + t * 16 + i * 4096, Ag + (size_t)i * 32 * K + k0);
      gld16((char*)Bt + t * 16 + i * 4096, Bg + (size_t)i * 32 * K + k0);
    }
    __syncthreads();
#pragma unroll
    for (int kk = 0; kk < 2; kk++) {
      bf16x8 a[4], b[4];
#pragma unroll
      for (int mt = 0; mt < 4; mt++)
        a[mt] = *(const bf16x8*)((const char*)At + aoff[kk][mt]);
#pragma unroll
      for (int nt = 0; nt < 4; nt++)
        b[nt] = *(const bf16x8*)((const char*)Bt + boff[kk][nt]);
#pragma unroll
      for (int mt = 0; mt < 4; mt++)
#pragma unroll
        for (int nt = 0; nt < 4; nt++)
          acc[mt][nt] = __builtin_amdgcn_mfma_f32_16x16x32_bf16(
              a[mt], b[nt], acc[mt][nt], 0, 0, 0);
    }
    __syncthreads();                       // also frees smem for epilogue
  }

  // ---- epilogue ----
  if constexpr (MODE == 0) {
    const int which0 = n0 >> 10;           // block tile is purely q, k, or v
    if (which0 == 2) {                     // V: [b,h,d,tok] transposed
#pragma unroll
      for (int mt = 0; mt < 4; mt++)
#pragma unroll
        for (int nt = 0; nt < 4; nt++) {
          const int mb = m0 + wm + mt * 16 + lhi * 4;
          const int c  = (n0 + wn + nt * 16 + l15) & 1023;
          const int hh = c >> 6, dd = c & 63;
          const int bb = mb >> 11, tok = mb & 2047;
          s16x4 pk;
#pragma unroll
          for (int j = 0; j < 4; j++) pk[j] = to_bf16(acc[mt][nt][j]);
          *(s16x4*)((short*)out2 +
                    (size_t)((bb * HEADS + hh) * DK + dd) * NTOK + tok) = pk;
        }
    } else {                               // q / k via LDS-coalesced strip
      char* strip = (char*)smem + w * 8192;    // 64 rows x 128B
      const float scl = (which0 == 0) ? QSCALE : 1.0f;
#pragma unroll
      for (int mt = 0; mt < 4; mt++)
#pragma unroll
        for (int nt = 0; nt < 4; nt++)
#pragma unroll
          for (int j = 0; j < 4; j++)
            *(short*)(strip + (mt * 16 + lhi * 4 + j) * 128 +
                      (nt * 16 + l15) * 2) = to_bf16(acc[mt][nt][j] * scl);
      short* dst = (which0 == 0) ? (short*)out0 : (short*)out1;
      const int c0 = (n0 + wn) & 1023;
#pragma unroll
      for (int ps = 0; ps < 8; ps++) {
        const int row = ps * 8 + (lane >> 3);
        bf16x8 vv = *(const bf16x8*)(strip + row * 128 + (lane & 7) * 16);
        *(bf16x8*)(dst + (size_t)(m0 + wm + row) * 1024 + c0 + (lane & 7) * 8) = vv;
      }
    }
  } else if constexpr (MODE == 2) {
    // silu-gate: per-wave 64x32 strip (pairs halve the columns)
    char* strip = (char*)At + w * 4096;        // 64 rows x 64B
#pragma unroll
    for (int mt = 0; mt < 4; mt++)
#pragma unroll
      for (int nt = 0; nt < 4; nt++)
#pragma unroll
        for (int j = 0; j < 4; j++) {
          float v0 = acc[mt][nt][j];
          float v1 = __shfl_xor(v0, 1);        // partner column (u<->g)
          if ((lane & 1) == 0) {
            float su = v0 / (1.f + __expf(-v0));
            *(short*)(strip + (mt * 16 + lhi * 4 + j) * 64 +
                      (nt * 8 + (l15 >> 1)) * 2) = to_bf16(su * v1);
          }
        }
    const int gcol0 = (n0 + wn) >> 1;
#pragma unroll
    for (int ps = 0; ps < 4; ps++) {
      const int row = ps * 16 + (lane >> 2);
      bf16x8 vv = *(const bf16x8*)(strip + row * 64 + (lane & 3) * 16);
      *(bf16x8*)((short*)out0 + (size_t)(m0 + wm + row) * INNER +
                 gcol0 + (lane & 3) * 8) = vv;
    }
  } else {
    // MODE 1 / MODE 3: residual add, bf16 out, LDS-coalesced strip
    char* strip = (char*)smem + w * 8192;      // 64 rows x 128B
#pragma unroll
    for (int mt = 0; mt < 4; mt++)
#pragma unroll
      for (int nt = 0; nt < 4; nt++) {
        const int mb = m0 + wm + mt * 16 + lhi * 4;
        const int n  = n0 + wn + nt * 16 + l15;
#pragma unroll
        for (int j = 0; j < 4; j++) {
          const size_t idx = (size_t)(mb + j) * 1024 + n;
          float v = acc[mt][nt][j];
          if constexpr (MODE == 1) v += aux1[n] + aux0[idx];
          else                     v += from_bf16(auxb[idx]);
          *(short*)(strip + (mt * 16 + lhi * 4 + j) * 128 + (nt * 16 + l15) * 2)
              = to_bf16(v);
        }
      }
#pragma unroll
    for (int ps = 0; ps < 8; ps++) {
      const int row = ps * 8 + (lane >> 3);
      bf16x8 vv = *(const bf16x8*)(strip + row * 128 + (lane & 7) * 16);
      *(bf16x8*)((short*)out0 + (size_t)(m0 + wm + row) * 1024 +
                 n0 + wn + (lane & 7) * 8) = vv;
    }
  }
}

// ---------------------------------------------------------------------------
// Flash attention (round-10 measured optimum), swapped-QK^T, 2 q-sets/wave,
// double-buffered K/V. grid 1024 (XCD-chunked: 8 bh per XCD = 4MB = one L2).
// Block = 4 waves x 32 q rows. KV tile 64, 32 tiles. LDS = 32 KB:
// P packed into the DEAD K tile in per-wave 16-row strips (3-bit XOR
// swizzle; residual 2-way write conflicts measured free). Cross-wave hazard
// closed by barrier after kf loads. 4 blocks/CU resident.
// FIXED-MAX softmax: P = exp2(S) via raw v_exp_f32.
// ---------------------------------------------------------------------------
__global__ __launch_bounds__(256, 4)
void attn_k(const short* __restrict__ qb, const short* __restrict__ kb,
            const short* __restrict__ vtb, short* __restrict__ ob)
{
  __shared__ short Kt[2][64 * 64];
  __shared__ short Vt[2][64 * 64];
  const int t = threadIdx.x;
  const int lane = t & 63;
  const int l15 = lane & 15, lhi = lane >> 4;
  const int w = t >> 6;
  // XCD-chunked swizzle: 1024 blocks, 128 per XCD chunk (= 8 consecutive bh)
  const int wg = (blockIdx.x & 7) * 128 + (blockIdx.x >> 3);
  const int bh = wg >> 4;
  const int b = bh >> 4, h = bh & 15;
  const int q0 = (wg & 15) << 7;

  bf16x8 aq[2][2];
#pragma unroll
  for (int s = 0; s < 2; s++) {
    const short* qp = qb + (size_t)(b * NTOK + q0 + w * 32 + s * 16 + l15) * EMB
                         + h * DK + lhi * 8;
    aq[s][0] = *(const bf16x8*)qp;
    aq[s][1] = *(const bf16x8*)(qp + 32);
  }

  f32x4 acc[2][4];
  const f32x4 fz = {0.f, 0.f, 0.f, 0.f};
#pragma unroll
  for (int s = 0; s < 2; s++)
#pragma unroll
    for (int dt = 0; dt < 4; dt++) acc[s][dt] = fz;
  float l_run[2] = {0.f, 0.f};

  const int r = t >> 3, p = t & 7;
  const int psrc = p ^ (r & 7);
  const short* kg = kb  + (size_t)(b * NTOK + r) * EMB + h * DK + psrc * 8;
  const short* vg = vtb + (size_t)(bh * DK + r) * NTOK + psrc * 8;

  int kvoff[4][2];
#pragma unroll
  for (int x = 0; x < 4; x++)
#pragma unroll
    for (int kk = 0; kk < 2; kk++) {
      int row = x * 16 + l15;
      kvoff[x][kk] = row * 128 + ((kk * 64 + lhi * 16) ^ ((row & 7) << 4));
    }
  // P strip inside dead K[cur]: per-wave rows w*16+l15, stride 128B, swizzled
  const int prow = w * 16 + l15;
  int pw_[4], pr_[2];
#pragma unroll
  for (int kvt = 0; kvt < 4; kvt++)
    pw_[kvt] = prow * 128 + ((kvt * 32 + lhi * 8) ^ ((l15 & 7) << 4));
#pragma unroll
  for (int kk = 0; kk < 2; kk++)
    pr_[kk] = prow * 128 + ((kk * 64 + lhi * 16) ^ ((l15 & 7) << 4));

  auto stage = [&](short* Kd, short* Vd, int kv0) {
    const short* ks = kg + (size_t)kv0 * EMB;
    const short* vs = vg + kv0;
    gld16(Kd + t * 8,        ks);
    gld16(Kd + t * 8 + 2048, ks + (size_t)32 * EMB);
    gld16(Vd + t * 8,        vs);
    gld16(Vd + t * 8 + 2048, vs + (size_t)32 * NTOK);
  };

  // fixed-max softmax + P pack into dead-K strip; returns B-frags
  auto do_set = [&](f32x4 (&sv)[4], float& lr, char* Pb, bf16x8 (&pb)[2]) {
    float ls = 0.f;
#pragma unroll
    for (int kvt = 0; kvt < 4; kvt++)
#pragma unroll
      for (int j = 0; j < 4; j++) {
        float pe = exp2_raw(sv[kvt][j]);
        sv[kvt][j] = pe;
        ls += pe;
      }
    lr += ls;
#pragma unroll
    for (int kvt = 0; kvt < 4; kvt++) {
      uint2 u;
      u.x = cvt_pk_bf16(sv[kvt][0], sv[kvt][1]);
      u.y = cvt_pk_bf16(sv[kvt][2], sv[kvt][3]);
      *(uint2*)(Pb + pw_[kvt]) = u;
    }
#pragma unroll
    for (int kk = 0; kk < 2; kk++)
      pb[kk] = *(const bf16x8*)(Pb + pr_[kk]);
  };

  auto compute = [&](int cur) {
    char* Kb = (char*)&Kt[cur][0];
    const char* Vb = (const char*)&Vt[cur][0];
    bf16x8 kf[4][2];
#pragma unroll
    for (int x = 0; x < 4; x++)
#pragma unroll
      for (int kk = 0; kk < 2; kk++)
        kf[x][kk] = *(const bf16x8*)(Kb + kvoff[x][kk]);
    // all waves must finish K reads before any P write lands in K[cur]
    asm volatile("s_waitcnt lgkmcnt(0)" ::: "memory");
    __builtin_amdgcn_sched_barrier(0);
    __builtin_amdgcn_s_barrier();          // barrier_B
    f32x4 s0[4], s1[4];
    __builtin_amdgcn_s_setprio(1);
#pragma unroll
    for (int kvt = 0; kvt < 4; kvt++) {
      s0[kvt] = __builtin_amdgcn_mfma_f32_16x16x32_bf16(kf[kvt][0], aq[0][0], fz, 0, 0, 0);
      s0[kvt] = __builtin_amdgcn_mfma_f32_16x16x32_bf16(kf[kvt][1], aq[0][1], s0[kvt], 0, 0, 0);
      s1[kvt] = __builtin_amdgcn_mfma_f32_16x16x32_bf16(kf[kvt][0], aq[1][0], fz, 0, 0, 0);
      s1[kvt] = __builtin_amdgcn_mfma_f32_16x16x32_bf16(kf[kvt][1], aq[1][1], s1[kvt], 0, 0, 0);
    }
    __builtin_amdgcn_s_setprio(0);
    bf16x8 pb0[2], pb1[2];
    do_set(s0, l_run[0], Kb, pb0);         // set 0: write strip, read frags
    do_set(s1, l_run[1], Kb, pb1);         // set 1: overwrite same strip
    bf16x8 vf[4][2];
#pragma unroll
    for (int dt = 0; dt < 4; dt++)
#pragma unroll
      for (int kk = 0; kk < 2; kk++)
        vf[dt][kk] = *(const bf16x8*)(Vb + kvoff[dt][kk]);
    __builtin_amdgcn_s_setprio(1);
#pragma unroll
    for (int dt = 0; dt < 4; dt++) {
#pragma unroll
      for (int kk = 0; kk < 2; kk++)
        acc[0][dt] = __builtin_amdgcn_mfma_f32_16x16x32_bf16(vf[dt][kk], pb0[kk], acc[0][dt], 0, 0, 0);
#pragma unroll
      for (int kk = 0; kk < 2; kk++)
        acc[1][dt] = __builtin_amdgcn_mfma_f32_16x16x32_bf16(vf[dt][kk], pb1[kk], acc[1][dt], 0, 0, 0);
    }
    __builtin_amdgcn_s_setprio(0);
  };

  // main loop: per tile: [vmcnt(0); barrier_A; stage(next); compute(cur)]
  stage(&Kt[0][0], &Vt[0][0], 0);
  for (int it = 0; it < 32; ++it) {
    const int cur = it & 1;
    asm volatile("s_waitcnt vmcnt(0)" ::: "memory");
    __builtin_amdgcn_s_barrier();          // barrier_A
    if (it + 1 < 32)
      stage(&Kt[cur ^ 1][0], &Vt[cur ^ 1][0], (it + 1) * 64);
    compute(cur);
  }

#pragma unroll
  for (int s = 0; s < 2; s++) {
    float lt = l_run[s];
    lt += __shfl_xor(lt, 16);
    lt += __shfl_xor(lt, 32);
    const float inv = 1.f / lt;
    short* op = ob + (size_t)(b * NTOK + q0 + w * 32 + s * 16 + l15) * EMB + h * DK;
#pragma unroll
    for (int dt = 0; dt < 4; dt++) {
      s16x4 pk;
#pragma unroll
      for (int j = 0; j < 4; j++) pk[j] = to_bf16(acc[s][dt][j] * inv);
      *(s16x4*)(op + dt * 16 + lhi * 4) = pk;
    }
  }
}

// ---------------------------------------------------------------------------
// RMSNorm over rows of 1024 bf16. OM=0: fp32 out. OM=1: bf16 out.
// ---------------------------------------------------------------------------
template<int OM>
__global__ __launch_bounds__(256, 4)
void rmsnorm_k(const short* __restrict__ in, const float* __restrict__ gw,
               float* __restrict__ of, short* __restrict__ ob)
{
  const int row = blockIdx.x;
  const int t = threadIdx.x;
  const s16x4 vb = ((const s16x4*)(in + (size_t)row * EMB))[t];
  float v0 = from_bf16(vb[0]), v1 = from_bf16(vb[1]);
  float v2 = from_bf16(vb[2]), v3 = from_bf16(vb[3]);
  float ss = v0 * v0 + v1 * v1 + v2 * v2 + v3 * v3;
#pragma unroll
  for (int off = 1; off < 64; off <<= 1) ss += __shfl_xor(ss, off);
  __shared__ float red[4];
  if ((t & 63) == 0) red[t >> 6] = ss;
  __syncthreads();
  float tot = red[0] + red[1] + red[2] + red[3];
  const float rinv = rsqrtf(tot * (1.f / EMB) + 1e-6f);
  const float4 g4 = ((const float4*)gw)[t];
  float o0 = v0 * rinv * g4.x, o1 = v1 * rinv * g4.y;
  float o2 = v2 * rinv * g4.z, o3 = v3 * rinv * g4.w;
  if (OM == 0) {
    float4 o; o.x = o0; o.y = o1; o.z = o2; o.w = o3;
    ((float4*)(of + (size_t)row * EMB))[t] = o;
  } else {
    s16x4 pk;
    pk[0] = to_bf16(o0); pk[1] = to_bf16(o1);
    pk[2] = to_bf16(o2); pk[3] = to_bf16(o3);
    ((s16x4*)(ob + (size_t)row * EMB))[t] = pk;
  }
}

// ---------------------------------------------------------------------------
extern "C" void kernel_launch(void* const* d_in, const int* in_sizes, int n_in,
                              void* d_out, int out_size, void* d_ws, size_t ws_size,
                              hipStream_t stream)
{
  const float* x  = (const float*)d_in[0];
  const float* Wq = (const float*)d_in[1];
  const float* Wk = (const float*)d_in[2];
  const float* Wv = (const float*)d_in[3];
  const float* Wc = (const float*)d_in[4];
  const float* bc = (const float*)d_in[5];
  const float* g1 = (const float*)d_in[6];
  const float* g2 = (const float*)d_in[7];
  const float* L1 = (const float*)d_in[8];
  const float* L2 = (const float*)d_in[9];
  const float* L3 = (const float*)d_in[10];
  float* out = (float*)d_out;

  char* ws = (char*)d_ws;
  size_t o = 0;
  auto take = [&](size_t bytes) -> char* {
    char* pp = ws + o;
    o += (bytes + 255) & ~(size_t)255;
    return pp;
  };
  short* xb   = (short*)take((size_t)MROWS * EMB * 2);
  short* wqkv = (short*)take((size_t)3072 * 1024 * 2);
  short* wcb  = (short*)take((size_t)1024 * 1024 * 2);
  short* l12  = (short*)take((size_t)5632 * 1024 * 2);
  short* l3b  = (short*)take((size_t)1024 * 2816 * 2);
  short* q    = (short*)take((size_t)MROWS * EMB * 2);
  short* k    = (short*)take((size_t)MROWS * EMB * 2);
  short* v    = (short*)take((size_t)MROWS * EMB * 2);
  short* attn = (short*)take((size_t)MROWS * EMB * 2);
  short* t1b  = (short*)take((size_t)MROWS * EMB * 2);
  short* hb   = (short*)take((size_t)MROWS * EMB * 2);
  short* gated = q;   // reuse q/k/v region (dead after attention)
  short* t2b   = t1b; // reuse t1b (dead after norm1)

  // all f32->bf16 conversions in one launch
  cvt_all<<<17920, 256, 0, stream>>>(x, Wq, Wk, Wv, Wc, L1, L2, L3,
                                     xb, wqkv, wcb, l12, l3b);

  // QKV projection (N = 3072 = q|k|v); q output pre-scaled by QSCALE
  gemm_bt<0><<<64 * 24, 256, 0, stream>>>(xb, wqkv, MROWS, 3072, 1024,
                                          q, k, v, nullptr, nullptr, nullptr);
  // attention (128 q rows per block, 1024 blocks = 4/CU all-resident)
  attn_k<<<1024, 256, 0, stream>>>(q, k, v, attn);
  // Wc projection + bias + residual -> t1b (bf16)
  gemm_bt<1><<<64 * 8, 256, 0, stream>>>(attn, wcb, MROWS, 1024, 1024,
                                         t1b, nullptr, nullptr, x, bc, nullptr);
  // h = rmsnorm(t1b, g1) -> bf16
  rmsnorm_k<1><<<MROWS, 256, 0, stream>>>(t1b, g1, nullptr, hb);
  // gated MLP up: interleaved u,g columns, fused silu-gate -> gated (bf16)
  gemm_bt<2><<<64 * 44, 256, 0, stream>>>(hb, l12, MROWS, 5632, 1024,
                                          gated, nullptr, nullptr,
                                          nullptr, nullptr, nullptr);
  // down proj + residual h (bf16) -> t2b (bf16)
  gemm_bt<3><<<64 * 8, 256, 0, stream>>>(gated, l3b, MROWS, 1024, 2816,
                                         t2b, nullptr, nullptr,
                                         nullptr, nullptr, hb);
  // final norm -> d_out (fp32)
  rmsnorm_k<0><<<MROWS, 256, 0, stream>>>(t2b, g2, out, nullptr);
}

// Round 17
// 382.248 us; speedup vs baseline: 1.0033x; 1.0033x over previous
//
#include <hip/hip_runtime.h>
#include <hip/hip_bf16.h>

// ---------------------------------------------------------------------------
// EncoderLayer on MI355X (gfx950), bf16 MFMA pipeline.
//   x[4,2048,1024] -> QKV proj -> MHA (flash, fixed-max softmax) -> Wc+bias+res
//   -> RMSNorm -> gated MLP (silu(h@L1.T)*(h@L2.T))@L3.T + res -> RMSNorm
// Round 17 = verbatim revert to the round-15 measured optimum (382.6 us).
// ---------------------------------------------------------------------------

#define EMB   1024
#define HEADS 16
#define DK    64
#define INNER 2816
#define BATCH 4
#define NTOK  2048
#define MROWS (BATCH * NTOK)   // 8192

// q pre-scale: 1/sqrt(64) * log2(e)  (softmax done in exp2 domain)
#define QSCALE 0.18033688011112042f

typedef short bf16x8 __attribute__((ext_vector_type(8)));
typedef short s16x4  __attribute__((ext_vector_type(4)));
typedef float f32x4  __attribute__((ext_vector_type(4)));

typedef const void __attribute__((address_space(1)))* gas_cvp;
typedef void       __attribute__((address_space(3)))* las_vp;

__device__ __forceinline__ short to_bf16(float f) {
  union { float f; unsigned u; } x; x.f = f;
  unsigned r = x.u + 0x7FFFu + ((x.u >> 16) & 1u);   // RNE
  return (short)(r >> 16);
}

__device__ __forceinline__ float from_bf16(short s) {
  union { unsigned u; float f; } x;
  x.u = ((unsigned)(unsigned short)s) << 16;
  return x.f;
}

// packed f32x2 -> bf16x2 (low = a, high = b)
__device__ __forceinline__ unsigned cvt_pk_bf16(float a, float b) {
  unsigned r;
  asm("v_cvt_pk_bf16_f32 %0, %1, %2" : "=v"(r) : "v"(a), "v"(b));
  return r;
}

// raw v_exp_f32 (2^x): 1 instruction, flush-to-zero below 2^-126 (fine here;
// libm exp2f expands to a denormal-safe multi-inst sequence we don't need)
__device__ __forceinline__ float exp2_raw(float x) {
#if __has_builtin(__builtin_amdgcn_exp2f)
  return __builtin_amdgcn_exp2f(x);
#else
  float r;
  asm("v_exp_f32 %0, %1" : "=v"(r) : "v"(x));
  return r;
#endif
}

// async global->LDS, 16B per lane; LDS dest must be linear (base + lane*16)
__device__ __forceinline__ void gld16(void* lds, const void* g) {
  __builtin_amdgcn_global_load_lds((gas_cvp)g, (las_vp)lds, 16, 0, 0);
}

// ---------------------------------------------------------------------------
// Merged f32 -> bf16 conversions (one launch).
// ---------------------------------------------------------------------------
__global__ __launch_bounds__(256, 4)
void cvt_all(const float* __restrict__ x,  const float* __restrict__ Wq,
             const float* __restrict__ Wk, const float* __restrict__ Wv,
             const float* __restrict__ Wc, const float* __restrict__ L1,
             const float* __restrict__ L2, const float* __restrict__ L3,
             short* __restrict__ xb, short* __restrict__ wqkv,
             short* __restrict__ wcb, short* __restrict__ l12,
             short* __restrict__ l3b)
{
  const int blk = blockIdx.x, tt = threadIdx.x;
  auto conv4 = [&](const float* s, short* d, int i) {
    float4 v = ((const float4*)s)[i];
    s16x4 o;
    o[0] = to_bf16(v.x); o[1] = to_bf16(v.y);
    o[2] = to_bf16(v.z); o[3] = to_bf16(v.w);
    ((s16x4*)d)[i] = o;
  };
  if (blk < 8192)       conv4(x,  xb,                 blk * 256 + tt);
  else if (blk < 9216)  conv4(Wq, wqkv,               (blk - 8192) * 256 + tt);
  else if (blk < 10240) conv4(Wk, wqkv + 1024 * 1024, (blk - 9216) * 256 + tt);
  else if (blk < 11264) conv4(Wv, wqkv + 2 * 1024 * 1024, (blk - 10240) * 256 + tt);
  else if (blk < 12288) conv4(Wc, wcb,                (blk - 11264) * 256 + tt);
  else if (blk < 15104) conv4(L3, l3b,                (blk - 12288) * 256 + tt);
  else {
    int i = (blk - 15104) * 256 + tt;      // over INNER*256 float4 slots
    int row = i >> 8, c4 = i & 255;
    float4 v1 = ((const float4*)L1)[i];
    float4 v2 = ((const float4*)L2)[i];
    s16x4 o1, o2;
    o1[0]=to_bf16(v1.x); o1[1]=to_bf16(v1.y); o1[2]=to_bf16(v1.z); o1[3]=to_bf16(v1.w);
    o2[0]=to_bf16(v2.x); o2[1]=to_bf16(v2.y); o2[2]=to_bf16(v2.z); o2[3]=to_bf16(v2.w);
    ((s16x4*)l12)[(size_t)(2 * row) * 256 + c4]     = o1;
    ((s16x4*)l12)[(size_t)(2 * row + 1) * 256 + c4] = o2;
  }
}

// ---------------------------------------------------------------------------
// 128x128 GEMM (m97 structure), C[M,N] = A[M,K] @ B[N,K]^T, BK=64.
// XCD-swizzled block mapping (grid % 8 == 0).
// MODE 0: QKV  -> out0=q(pre-scaled), out1=k std, out2=v transposed [b,h,d,tok]
// MODE 1: Wc   -> out0 = bf16(acc + bc[n](aux1) + x[m,n](aux0))
// MODE 2: MLP12 interleaved u,g -> out0 = bf16(silu(u)*g), N/2 cols
// MODE 3: L3   -> out0 = bf16(acc + bf16(hb[m,n])(auxb))
// ---------------------------------------------------------------------------
template<int MODE>
__global__ __launch_bounds__(256, 3)
void gemm_bt(const short* __restrict__ A, const short* __restrict__ Bw,
             int M, int N, int K,
             void* __restrict__ out0, void* __restrict__ out1,
             void* __restrict__ out2,
             const float* __restrict__ aux0, const float* __restrict__ aux1,
             const short* __restrict__ auxb)
{
  __shared__ short At[128 * 64];
  __shared__ short Bt[128 * 64];
  const int t = threadIdx.x;
  const int lane = t & 63;
  const int l15 = lane & 15, lhi = lane >> 4;
  const int w  = t >> 6;
  const int wm = (w >> 1) << 6;
  const int wn = (w & 1) << 6;
  // bijective XCD swizzle: consecutive wg on one XCD share A panels
  const int chunk = gridDim.x >> 3;
  const int wg = (blockIdx.x & 7) * chunk + (blockIdx.x >> 3);
  const int tilesN = N >> 7;
  const int m0 = (wg / tilesN) << 7;
  const int n0 = (wg % tilesN) << 7;

  const int r = t >> 3;
  const int p = t & 7;
  const int psrc = p ^ (r & 7);
  const short* Ag = A  + (size_t)(m0 + r) * K + psrc * 8;
  const short* Bg = Bw + (size_t)(n0 + r) * K + psrc * 8;

  f32x4 acc[4][4];
  const f32x4 fz = {0.f, 0.f, 0.f, 0.f};
#pragma unroll
  for (int i = 0; i < 4; i++)
#pragma unroll
    for (int j = 0; j < 4; j++) acc[i][j] = fz;

  int aoff[2][4], boff[2][4];
#pragma unroll
  for (int kk = 0; kk < 2; kk++)
#pragma unroll
    for (int mt = 0; mt < 4; mt++) {
      int ra = wm + mt * 16 + l15;
      aoff[kk][mt] = ra * 128 + ((kk * 64 + lhi * 16) ^ ((ra & 7) << 4));
      int rb = wn + mt * 16 + l15;
      boff[kk][mt] = rb * 128 + ((kk * 64 + lhi * 16) ^ ((rb & 7) << 4));
    }

  for (int k0 = 0; k0 < K; k0 += 64) {
#pragma unroll
    for (int i = 0; i < 4; i++) {
      gld16((char*)At + t * 16 + i * 4096, Ag + (size_t)i * 32 * K + k0);
      gld16((char*)Bt + t * 16 + i * 4096, Bg + (size_t)i * 32 * K + k0);
    }
    __syncthreads();
#pragma unroll
    for (int kk = 0; kk < 2; kk++) {
      bf16x8 a[4], b[4];
#pragma unroll
      for (int mt = 0; mt < 4; mt++)
        a[mt] = *(const bf16x8*)((const char*)At + aoff[kk][mt]);
#pragma unroll
      for (int nt = 0; nt < 4; nt++)
        b[nt] = *(const bf16x8*)((const char*)Bt + boff[kk][nt]);
#pragma unroll
      for (int mt = 0; mt < 4; mt++)
#pragma unroll
        for (int nt = 0; nt < 4; nt++)
          acc[mt][nt] = __builtin_amdgcn_mfma_f32_16x16x32_bf16(
              a[mt], b[nt], acc[mt][nt], 0, 0, 0);
    }
    __syncthreads();
  }

#pragma unroll
  for (int mt = 0; mt < 4; mt++) {
#pragma unroll
    for (int nt = 0; nt < 4; nt++) {
      const int mb = m0 + wm + mt * 16 + lhi * 4;
      const int n  = n0 + wn + nt * 16 + l15;
      if constexpr (MODE == 0) {
        const int which = n >> 10, c = n & 1023;
        if (which == 2) {                  // V: [b,h,d,tok] transposed
          const int hh = c >> 6, dd = c & 63;
          const int bb = mb >> 11, tok = mb & 2047;
          s16x4 pk;
#pragma unroll
          for (int j = 0; j < 4; j++) pk[j] = to_bf16(acc[mt][nt][j]);
          *(s16x4*)((short*)out2 +
                    (size_t)((bb * HEADS + hh) * DK + dd) * NTOK + tok) = pk;
        } else {
          short* dst = (which == 0) ? (short*)out0 : (short*)out1;
          const float scl = (which == 0) ? QSCALE : 1.0f;
#pragma unroll
          for (int j = 0; j < 4; j++)
            dst[(size_t)(mb + j) * 1024 + c] = to_bf16(acc[mt][nt][j] * scl);
        }
      } else if constexpr (MODE == 1) {
#pragma unroll
        for (int j = 0; j < 4; j++) {
          size_t idx = (size_t)(mb + j) * 1024 + n;
          ((short*)out0)[idx] = to_bf16(acc[mt][nt][j] + aux1[n] + aux0[idx]);
        }
      } else if constexpr (MODE == 2) {
#pragma unroll
        for (int j = 0; j < 4; j++) {
          float v0 = acc[mt][nt][j];
          float v1 = __shfl_xor(v0, 1);    // partner column (u<->g pair)
          if ((lane & 1) == 0) {
            float su = v0 / (1.f + __expf(-v0));   // silu(u)
            ((short*)out0)[(size_t)(mb + j) * INNER + (n >> 1)] =
                to_bf16(su * v1);
          }
        }
      } else {                             // MODE 3: + residual h (bf16)
#pragma unroll
        for (int j = 0; j < 4; j++) {
          size_t idx = (size_t)(mb + j) * 1024 + n;
          ((short*)out0)[idx] = to_bf16(acc[mt][nt][j] + from_bf16(auxb[idx]));
        }
      }
    }
  }
}

// ---------------------------------------------------------------------------
// Flash attention (round-10 measured optimum), swapped-QK^T, 2 q-sets/wave,
// double-buffered K/V. grid 1024 (XCD-chunked: 8 bh per XCD = 4MB = one L2).
// Block = 4 waves x 32 q rows. KV tile 64, 32 tiles. LDS = 32 KB:
// P packed into the DEAD K tile in per-wave 16-row strips (3-bit XOR
// swizzle; residual 2-way write conflicts measured free). Cross-wave hazard
// closed by barrier after kf loads. 4 blocks/CU resident.
// FIXED-MAX softmax: P = exp2(S) via raw v_exp_f32.
// ---------------------------------------------------------------------------
__global__ __launch_bounds__(256, 4)
void attn_k(const short* __restrict__ qb, const short* __restrict__ kb,
            const short* __restrict__ vtb, short* __restrict__ ob)
{
  __shared__ short Kt[2][64 * 64];
  __shared__ short Vt[2][64 * 64];
  const int t = threadIdx.x;
  const int lane = t & 63;
  const int l15 = lane & 15, lhi = lane >> 4;
  const int w = t >> 6;
  // XCD-chunked swizzle: 1024 blocks, 128 per XCD chunk (= 8 consecutive bh)
  const int wg = (blockIdx.x & 7) * 128 + (blockIdx.x >> 3);
  const int bh = wg >> 4;
  const int b = bh >> 4, h = bh & 15;
  const int q0 = (wg & 15) << 7;

  bf16x8 aq[2][2];
#pragma unroll
  for (int s = 0; s < 2; s++) {
    const short* qp = qb + (size_t)(b * NTOK + q0 + w * 32 + s * 16 + l15) * EMB
                         + h * DK + lhi * 8;
    aq[s][0] = *(const bf16x8*)qp;
    aq[s][1] = *(const bf16x8*)(qp + 32);
  }

  f32x4 acc[2][4];
  const f32x4 fz = {0.f, 0.f, 0.f, 0.f};
#pragma unroll
  for (int s = 0; s < 2; s++)
#pragma unroll
    for (int dt = 0; dt < 4; dt++) acc[s][dt] = fz;
  float l_run[2] = {0.f, 0.f};

  const int r = t >> 3, p = t & 7;
  const int psrc = p ^ (r & 7);
  const short* kg = kb  + (size_t)(b * NTOK + r) * EMB + h * DK + psrc * 8;
  const short* vg = vtb + (size_t)(bh * DK + r) * NTOK + psrc * 8;

  int kvoff[4][2];
#pragma unroll
  for (int x = 0; x < 4; x++)
#pragma unroll
    for (int kk = 0; kk < 2; kk++) {
      int row = x * 16 + l15;
      kvoff[x][kk] = row * 128 + ((kk * 64 + lhi * 16) ^ ((row & 7) << 4));
    }
  // P strip inside dead K[cur]: per-wave rows w*16+l15, stride 128B, swizzled
  const int prow = w * 16 + l15;
  int pw_[4], pr_[2];
#pragma unroll
  for (int kvt = 0; kvt < 4; kvt++)
    pw_[kvt] = prow * 128 + ((kvt * 32 + lhi * 8) ^ ((l15 & 7) << 4));
#pragma unroll
  for (int kk = 0; kk < 2; kk++)
    pr_[kk] = prow * 128 + ((kk * 64 + lhi * 16) ^ ((l15 & 7) << 4));

  auto stage = [&](short* Kd, short* Vd, int kv0) {
    const short* ks = kg + (size_t)kv0 * EMB;
    const short* vs = vg + kv0;
    gld16(Kd + t * 8,        ks);
    gld16(Kd + t * 8 + 2048, ks + (size_t)32 * EMB);
    gld16(Vd + t * 8,        vs);
    gld16(Vd + t * 8 + 2048, vs + (size_t)32 * NTOK);
  };

  // fixed-max softmax + P pack into dead-K strip; returns B-frags
  auto do_set = [&](f32x4 (&sv)[4], float& lr, char* Pb, bf16x8 (&pb)[2]) {
    float ls = 0.f;
#pragma unroll
    for (int kvt = 0; kvt < 4; kvt++)
#pragma unroll
      for (int j = 0; j < 4; j++) {
        float pe = exp2_raw(sv[kvt][j]);
        sv[kvt][j] = pe;
        ls += pe;
      }
    lr += ls;
#pragma unroll
    for (int kvt = 0; kvt < 4; kvt++) {
      uint2 u;
      u.x = cvt_pk_bf16(sv[kvt][0], sv[kvt][1]);
      u.y = cvt_pk_bf16(sv[kvt][2], sv[kvt][3]);
      *(uint2*)(Pb + pw_[kvt]) = u;
    }
#pragma unroll
    for (int kk = 0; kk < 2; kk++)
      pb[kk] = *(const bf16x8*)(Pb + pr_[kk]);
  };

  auto compute = [&](int cur) {
    char* Kb = (char*)&Kt[cur][0];
    const char* Vb = (const char*)&Vt[cur][0];
    bf16x8 kf[4][2];
#pragma unroll
    for (int x = 0; x < 4; x++)
#pragma unroll
      for (int kk = 0; kk < 2; kk++)
        kf[x][kk] = *(const bf16x8*)(Kb + kvoff[x][kk]);
    // all waves must finish K reads before any P write lands in K[cur]
    asm volatile("s_waitcnt lgkmcnt(0)" ::: "memory");
    __builtin_amdgcn_sched_barrier(0);
    __builtin_amdgcn_s_barrier();          // barrier_B
    f32x4 s0[4], s1[4];
    __builtin_amdgcn_s_setprio(1);
#pragma unroll
    for (int kvt = 0; kvt < 4; kvt++) {
      s0[kvt] = __builtin_amdgcn_mfma_f32_16x16x32_bf16(kf[kvt][0], aq[0][0], fz, 0, 0, 0);
      s0[kvt] = __builtin_amdgcn_mfma_f32_16x16x32_bf16(kf[kvt][1], aq[0][1], s0[kvt], 0, 0, 0);
      s1[kvt] = __builtin_amdgcn_mfma_f32_16x16x32_bf16(kf[kvt][0], aq[1][0], fz, 0, 0, 0);
      s1[kvt] = __builtin_amdgcn_mfma_f32_16x16x32_bf16(kf[kvt][1], aq[1][1], s1[kvt], 0, 0, 0);
    }
    __builtin_amdgcn_s_setprio(0);
    bf16x8 pb0[2], pb1[2];
    do_set(s0, l_run[0], Kb, pb0);         // set 0: write strip, read frags
    do_set(s1, l_run[1], Kb, pb1);         // set 1: overwrite same strip
    bf16x8 vf[4][2];
#pragma unroll
    for (int dt = 0; dt < 4; dt++)
#pragma unroll
      for (int kk = 0; kk < 2; kk++)
        vf[dt][kk] = *(const bf16x8*)(Vb + kvoff[dt][kk]);
    __builtin_amdgcn_s_setprio(1);
#pragma unroll
    for (int dt = 0; dt < 4; dt++) {
#pragma unroll
      for (int kk = 0; kk < 2; kk++)
        acc[0][dt] = __builtin_amdgcn_mfma_f32_16x16x32_bf16(vf[dt][kk], pb0[kk], acc[0][dt], 0, 0, 0);
#pragma unroll
      for (int kk = 0; kk < 2; kk++)
        acc[1][dt] = __builtin_amdgcn_mfma_f32_16x16x32_bf16(vf[dt][kk], pb1[kk], acc[1][dt], 0, 0, 0);
    }
    __builtin_amdgcn_s_setprio(0);
  };

  // main loop: per tile: [vmcnt(0); barrier_A; stage(next); compute(cur)]
  stage(&Kt[0][0], &Vt[0][0], 0);
  for (int it = 0; it < 32; ++it) {
    const int cur = it & 1;
    asm volatile("s_waitcnt vmcnt(0)" ::: "memory");
    __builtin_amdgcn_s_barrier();          // barrier_A
    if (it + 1 < 32)
      stage(&Kt[cur ^ 1][0], &Vt[cur ^ 1][0], (it + 1) * 64);
    compute(cur);
  }

#pragma unroll
  for (int s = 0; s < 2; s++) {
    float lt = l_run[s];
    lt += __shfl_xor(lt, 16);
    lt += __shfl_xor(lt, 32);
    const float inv = 1.f / lt;
    short* op = ob + (size_t)(b * NTOK + q0 + w * 32 + s * 16 + l15) * EMB + h * DK;
#pragma unroll
    for (int dt = 0; dt < 4; dt++) {
      s16x4 pk;
#pragma unroll
      for (int j = 0; j < 4; j++) pk[j] = to_bf16(acc[s][dt][j] * inv);
      *(s16x4*)(op + dt * 16 + lhi * 4) = pk;
    }
  }
}

// ---------------------------------------------------------------------------
// RMSNorm over rows of 1024 bf16. OM=0: fp32 out. OM=1: bf16 out.
// ---------------------------------------------------------------------------
template<int OM>
__global__ __launch_bounds__(256, 4)
void rmsnorm_k(const short* __restrict__ in, const float* __restrict__ gw,
               float* __restrict__ of, short* __restrict__ ob)
{
  const int row = blockIdx.x;
  const int t = threadIdx.x;
  const s16x4 vb = ((const s16x4*)(in + (size_t)row * EMB))[t];
  float v0 = from_bf16(vb[0]), v1 = from_bf16(vb[1]);
  float v2 = from_bf16(vb[2]), v3 = from_bf16(vb[3]);
  float ss = v0 * v0 + v1 * v1 + v2 * v2 + v3 * v3;
#pragma unroll
  for (int off = 1; off < 64; off <<= 1) ss += __shfl_xor(ss, off);
  __shared__ float red[4];
  if ((t & 63) == 0) red[t >> 6] = ss;
  __syncthreads();
  float tot = red[0] + red[1] + red[2] + red[3];
  const float rinv = rsqrtf(tot * (1.f / EMB) + 1e-6f);
  const float4 g4 = ((const float4*)gw)[t];
  float o0 = v0 * rinv * g4.x, o1 = v1 * rinv * g4.y;
  float o2 = v2 * rinv * g4.z, o3 = v3 * rinv * g4.w;
  if (OM == 0) {
    float4 o; o.x = o0; o.y = o1; o.z = o2; o.w = o3;
    ((float4*)(of + (size_t)row * EMB))[t] = o;
  } else {
    s16x4 pk;
    pk[0] = to_bf16(o0); pk[1] = to_bf16(o1);
    pk[2] = to_bf16(o2); pk[3] = to_bf16(o3);
    ((s16x4*)(ob + (size_t)row * EMB))[t] = pk;
  }
}

// ---------------------------------------------------------------------------
extern "C" void kernel_launch(void* const* d_in, const int* in_sizes, int n_in,
                              void* d_out, int out_size, void* d_ws, size_t ws_size,
                              hipStream_t stream)
{
  const float* x  = (const float*)d_in[0];
  const float* Wq = (const float*)d_in[1];
  const float* Wk = (const float*)d_in[2];
  const float* Wv = (const float*)d_in[3];
  const float* Wc = (const float*)d_in[4];
  const float* bc = (const float*)d_in[5];
  const float* g1 = (const float*)d_in[6];
  const float* g2 = (const float*)d_in[7];
  const float* L1 = (const float*)d_in[8];
  const float* L2 = (const float*)d_in[9];
  const float* L3 = (const float*)d_in[10];
  float* out = (float*)d_out;

  char* ws = (char*)d_ws;
  size_t o = 0;
  auto take = [&](size_t bytes) -> char* {
    char* pp = ws + o;
    o += (bytes + 255) & ~(size_t)255;
    return pp;
  };
  short* xb   = (short*)take((size_t)MROWS * EMB * 2);
  short* wqkv = (short*)take((size_t)3072 * 1024 * 2);
  short* wcb  = (short*)take((size_t)1024 * 1024 * 2);
  short* l12  = (short*)take((size_t)5632 * 1024 * 2);
  short* l3b  = (short*)take((size_t)1024 * 2816 * 2);
  short* q    = (short*)take((size_t)MROWS * EMB * 2);
  short* k    = (short*)take((size_t)MROWS * EMB * 2);
  short* v    = (short*)take((size_t)MROWS * EMB * 2);
  short* attn = (short*)take((size_t)MROWS * EMB * 2);
  short* t1b  = (short*)take((size_t)MROWS * EMB * 2);
  short* hb   = (short*)take((size_t)MROWS * EMB * 2);
  short* gated = q;   // reuse q/k/v region (dead after attention)
  short* t2b   = t1b; // reuse t1b (dead after norm1)

  // all f32->bf16 conversions in one launch
  cvt_all<<<17920, 256, 0, stream>>>(x, Wq, Wk, Wv, Wc, L1, L2, L3,
                                     xb, wqkv, wcb, l12, l3b);

  // QKV projection (N = 3072 = q|k|v); q output pre-scaled by QSCALE
  gemm_bt<0><<<64 * 24, 256, 0, stream>>>(xb, wqkv, MROWS, 3072, 1024,
                                          q, k, v, nullptr, nullptr, nullptr);
  // attention (128 q rows per block, 1024 blocks = 4/CU all-resident)
  attn_k<<<1024, 256, 0, stream>>>(q, k, v, attn);
  // Wc projection + bias + residual -> t1b (bf16)
  gemm_bt<1><<<64 * 8, 256, 0, stream>>>(attn, wcb, MROWS, 1024, 1024,
                                         t1b, nullptr, nullptr, x, bc, nullptr);
  // h = rmsnorm(t1b, g1) -> bf16
  rmsnorm_k<1><<<MROWS, 256, 0, stream>>>(t1b, g1, nullptr, hb);
  // gated MLP up: interleaved u,g columns, fused silu-gate -> gated (bf16)
  gemm_bt<2><<<64 * 44, 256, 0, stream>>>(hb, l12, MROWS, 5632, 1024,
                                          gated, nullptr, nullptr,
                                          nullptr, nullptr, nullptr);
  // down proj + residual h (bf16) -> t2b (bf16)
  gemm_bt<3><<<64 * 8, 256, 0, stream>>>(gated, l3b, MROWS, 1024, 2816,
                                         t2b, nullptr, nullptr,
                                         nullptr, nullptr, hb);
  // final norm -> d_out (fp32)
  rmsnorm_k<0><<<MROWS, 256, 0, stream>>>(t2b, g2, out, nullptr);
}